// Round 3
// baseline (1216.778 us; speedup 1.0000x reference)
//
#include <hip/hip_runtime.h>

#define NQ   100000
#define PP   8
#define CC   256
#define HIDN 256
#define HH   512
#define WW   512
#define DD   258
#define KK1  288      // layer-1 K padded to 9*32
#define KK2  256
#define TQ   32       // queries per block (mlp)
#define NTHR 512      // 8 waves: each owns a 32-col n-slice x 2 m-tiles
#define XS_STRIDE 296 // bf16 elems per row (16B-aligned + 2-way-conflict-free for b128 frag reads)
#define GQB  4        // queries per gather block (1 per wave)

typedef __attribute__((ext_vector_type(8))) __bf16 bf16x8;
typedef __attribute__((ext_vector_type(4))) float  f32x4;
typedef __attribute__((ext_vector_type(4))) unsigned short u16x4;
typedef __attribute__((ext_vector_type(8))) unsigned short u16x8;

__device__ __forceinline__ unsigned short f2bf_hi(float v, float* rem) {
    __bf16 h = (__bf16)v;
    *rem = v - (float)h;
    return __builtin_bit_cast(unsigned short, h);
}
__device__ __forceinline__ unsigned short f2bf(float v) {
    __bf16 h = (__bf16)v;
    return __builtin_bit_cast(unsigned short, h);
}
__device__ __forceinline__ float bf2f(unsigned short h) {
    unsigned int u = ((unsigned int)h) << 16;
    return __builtin_bit_cast(float, u);
}

// ---------------- ws layout (bytes) ----------------
#define WS_W1TH 0
#define WS_W1TL 294912
#define WS_W2TH 589824
#define WS_W2TL 851968
#define WS_W3T  1114112
#define WS_B1E  1138688
#define WS_SP   1140736   // [NQ][8] float4 {bitcast(cell), wx, wy, nwp} = 12.8 MB

// ---------------------------------------------------------------------------
// prep: fold LN affine into W1, transpose + zero-pad + bf16 hi/lo split
// ---------------------------------------------------------------------------
__global__ void prep_w1(const float* __restrict__ og, const float* __restrict__ obl,
                        const float* __restrict__ oW1, const float* __restrict__ ob1,
                        const float* __restrict__ wg, const float* __restrict__ wbl,
                        const float* __restrict__ wW1, const float* __restrict__ wb1,
                        unsigned short* __restrict__ w1th, unsigned short* __restrict__ w1tl,
                        float* __restrict__ b1e) {
    const int br = blockIdx.y, k = blockIdx.x, n = threadIdx.x;
    const float* g  = br ? wg  : og;
    const float* bl = br ? wbl : obl;
    const float* W1 = br ? wW1 : oW1;
    const float* b1 = br ? wb1 : ob1;
    float v = (k < DD) ? g[k] * W1[k * HIDN + n] : 0.f;
    float rem; unsigned short hi = f2bf_hi(v, &rem);
    size_t o = (size_t)br * 256 * KK1 + (size_t)n * KK1 + k;
    w1th[o] = hi; w1tl[o] = f2bf(rem);
    if (k == 0) {
        // 4-way unrolled partial sums: break the serial dependent-load chain
        float a0 = 0.f, a1 = 0.f, a2 = 0.f, a3 = 0.f;
        for (int kk = 0; kk < 256; kk += 4) {
            a0 += bl[kk + 0] * W1[(kk + 0) * HIDN + n];
            a1 += bl[kk + 1] * W1[(kk + 1) * HIDN + n];
            a2 += bl[kk + 2] * W1[(kk + 2) * HIDN + n];
            a3 += bl[kk + 3] * W1[(kk + 3) * HIDN + n];
        }
        float s = b1[n] + a0 + a1 + a2 + a3
                + bl[256] * W1[256 * HIDN + n] + bl[257] * W1[257 * HIDN + n];
        b1e[br * 256 + n] = s;
    }
}

__global__ void prep_w2(const float* __restrict__ oW2, const float* __restrict__ wW2,
                        unsigned short* __restrict__ w2th, unsigned short* __restrict__ w2tl) {
    const int br = blockIdx.y, k = blockIdx.x, n = threadIdx.x;
    const float* W2 = br ? wW2 : oW2;
    float v = W2[k * HIDN + n];
    float rem; unsigned short hi = f2bf_hi(v, &rem);
    size_t o = (size_t)br * 256 * KK2 + (size_t)n * KK2 + k;
    w2th[o] = hi; w2tl[o] = f2bf(rem);
}

__global__ void prep_w3(const float* __restrict__ oW3, const float* __restrict__ wW3,
                        float* __restrict__ w3t) {
    const int br = blockIdx.x, t = threadIdx.x;
    if (br == 0) {
        const int c = t & 15, kb = t >> 4;
        for (int i = 0; i < 16; ++i) { int k = kb * 16 + i; w3t[c * 256 + k] = oW3[k * 16 + c]; }
    } else {
        const int c = t & 7, kb = t >> 3;
        for (int i = 0; i < 8; ++i)  { int k = kb * 8 + i;  w3t[(16 + c) * 256 + k] = wW3[k * 8 + c]; }
    }
}

// ---------------------------------------------------------------------------
// mlp: reg-LN -> (MFMA split-bf16 L1,L2 + L3) x2 -> softmax/tanh -> sp records
// ---------------------------------------------------------------------------
__launch_bounds__(NTHR, 4)
__global__ void mlp_kernel(const float* __restrict__ gq, const float* __restrict__ pc,
                           const unsigned short* __restrict__ w1th, const unsigned short* __restrict__ w1tl,
                           const unsigned short* __restrict__ w2th, const unsigned short* __restrict__ w2tl,
                           const float* __restrict__ w3t, const float* __restrict__ b1e,
                           const float* __restrict__ ob2, const float* __restrict__ ob3,
                           const float* __restrict__ wb2, const float* __restrict__ wb3,
                           float4* __restrict__ sp) {
    __shared__ __align__(16) unsigned short xsh[TQ * XS_STRIDE];
    __shared__ __align__(16) unsigned short xsl[TQ * XS_STRIDE];
    __shared__ __align__(16) float raw[TQ * 24];
    __shared__ __align__(16) float pcs[TQ * 2];

    const int t    = threadIdx.x;
    const int q0   = blockIdx.x * TQ;
    const int lane = t & 63;
    const int wv   = t >> 6;       // 0..7
    const int quad = lane >> 4;
    const int l15  = lane & 15;

    for (int i = t; i < TQ * XS_STRIDE / 2; i += NTHR) {
        ((unsigned int*)xsh)[i] = 0u; ((unsigned int*)xsl)[i] = 0u;
    }
    if (t < TQ * 2) pcs[t] = pc[(size_t)q0 * 2 + t];
    __syncthreads();

    const float4* gq4 = (const float4*)gq;

    for (int br = 0; br < 2; ++br) {
        // ---- layernorm from registers -> xs hi/lo ----
        #pragma unroll
        for (int qq = 0; qq < 4; ++qq) {
            const int q = wv * 4 + qq;
            const float4 v = gq4[(size_t)(q0 + q) * 64 + lane];
            const float px = pcs[q * 2 + 0], py = pcs[q * 2 + 1];
            float s  = v.x + v.y + v.z + v.w;
            float ss = v.x * v.x + v.y * v.y + v.z * v.z + v.w * v.w;
            if (lane == 0) { s += px + py; ss += px * px + py * py; }
            #pragma unroll
            for (int off = 32; off > 0; off >>= 1) {
                s += __shfl_xor(s, off, 64); ss += __shfl_xor(ss, off, 64);
            }
            const float mu = s * (1.f / DD);
            const float var = fmaxf(ss * (1.f / DD) - mu * mu, 0.f);
            const float rs = rsqrtf(var + 1e-5f);
            const float n0 = (v.x - mu) * rs, n1 = (v.y - mu) * rs;
            const float n2 = (v.z - mu) * rs, n3 = (v.w - mu) * rs;
            float r0, r1, r2, r3;
            u16x4 hh; u16x4 ll;
            hh[0] = f2bf_hi(n0, &r0); hh[1] = f2bf_hi(n1, &r1);
            hh[2] = f2bf_hi(n2, &r2); hh[3] = f2bf_hi(n3, &r3);
            ll[0] = f2bf(r0); ll[1] = f2bf(r1); ll[2] = f2bf(r2); ll[3] = f2bf(r3);
            *(u16x4*)(&xsh[q * XS_STRIDE + lane * 4]) = hh;
            *(u16x4*)(&xsl[q * XS_STRIDE + lane * 4]) = ll;
            if (lane == 0) {
                const float nx = (px - mu) * rs, ny = (py - mu) * rs;
                float rx, ry;
                xsh[q * XS_STRIDE + 256] = f2bf_hi(nx, &rx);
                xsh[q * XS_STRIDE + 257] = f2bf_hi(ny, &ry);
                xsl[q * XS_STRIDE + 256] = f2bf(rx);
                xsl[q * XS_STRIDE + 257] = f2bf(ry);
            }
        }
        __syncthreads();

        // ---- layer 1: hA = relu(x @ W1eff + b1eff) ----
        {
            f32x4 acc[2][2];
            #pragma unroll
            for (int mt = 0; mt < 2; ++mt)
                #pragma unroll
                for (int nt = 0; nt < 2; ++nt) {
                    float b = b1e[br * 256 + wv * 32 + nt * 16 + l15];
                    acc[mt][nt] = (f32x4){b, b, b, b};
                }
            const unsigned short* Wh = w1th + (size_t)br * 256 * KK1;
            const unsigned short* Wl = w1tl + (size_t)br * 256 * KK1;
            const unsigned short* a0h = xsh + l15 * XS_STRIDE + quad * 8;
            const unsigned short* a0l = xsl + l15 * XS_STRIDE + quad * 8;
            const unsigned short* a1h = a0h + 16 * XS_STRIDE;
            const unsigned short* a1l = a0l + 16 * XS_STRIDE;
            for (int k0 = 0; k0 < KK1; k0 += 32) {
                const bf16x8 ah0 = *(const bf16x8*)(a0h + k0);
                const bf16x8 al0 = *(const bf16x8*)(a0l + k0);
                const bf16x8 ah1 = *(const bf16x8*)(a1h + k0);
                const bf16x8 al1 = *(const bf16x8*)(a1l + k0);
                #pragma unroll
                for (int nt = 0; nt < 2; ++nt) {
                    const size_t n = wv * 32 + nt * 16 + l15;
                    const bf16x8 bh = *(const bf16x8*)(Wh + n * KK1 + k0 + quad * 8);
                    const bf16x8 bl = *(const bf16x8*)(Wl + n * KK1 + k0 + quad * 8);
                    acc[0][nt] = __builtin_amdgcn_mfma_f32_16x16x32_bf16(ah0, bh, acc[0][nt], 0, 0, 0);
                    acc[0][nt] = __builtin_amdgcn_mfma_f32_16x16x32_bf16(ah0, bl, acc[0][nt], 0, 0, 0);
                    acc[0][nt] = __builtin_amdgcn_mfma_f32_16x16x32_bf16(al0, bh, acc[0][nt], 0, 0, 0);
                    acc[1][nt] = __builtin_amdgcn_mfma_f32_16x16x32_bf16(ah1, bh, acc[1][nt], 0, 0, 0);
                    acc[1][nt] = __builtin_amdgcn_mfma_f32_16x16x32_bf16(ah1, bl, acc[1][nt], 0, 0, 0);
                    acc[1][nt] = __builtin_amdgcn_mfma_f32_16x16x32_bf16(al1, bh, acc[1][nt], 0, 0, 0);
                }
            }
            __syncthreads();   // all waves done READING x from xs
            #pragma unroll
            for (int mt = 0; mt < 2; ++mt)
                #pragma unroll
                for (int nt = 0; nt < 2; ++nt) {
                    const int n = wv * 32 + nt * 16 + l15;
                    #pragma unroll
                    for (int r = 0; r < 4; ++r) {
                        const int m = mt * 16 + quad * 4 + r;
                        float v = fmaxf(acc[mt][nt][r], 0.f);
                        float rem;
                        xsh[m * XS_STRIDE + n] = f2bf_hi(v, &rem);
                        xsl[m * XS_STRIDE + n] = f2bf(rem);
                    }
                }
        }
        __syncthreads();

        // ---- layer 2: h2 = relu(hA @ W2 + b2) ----
        {
            const float* b2 = br ? wb2 : ob2;
            f32x4 acc[2][2];
            #pragma unroll
            for (int mt = 0; mt < 2; ++mt)
                #pragma unroll
                for (int nt = 0; nt < 2; ++nt) {
                    float b = b2[wv * 32 + nt * 16 + l15];
                    acc[mt][nt] = (f32x4){b, b, b, b};
                }
            const unsigned short* Wh = w2th + (size_t)br * 256 * KK2;
            const unsigned short* Wl = w2tl + (size_t)br * 256 * KK2;
            const unsigned short* a0h = xsh + l15 * XS_STRIDE + quad * 8;
            const unsigned short* a0l = xsl + l15 * XS_STRIDE + quad * 8;
            const unsigned short* a1h = a0h + 16 * XS_STRIDE;
            const unsigned short* a1l = a0l + 16 * XS_STRIDE;
            for (int k0 = 0; k0 < KK2; k0 += 32) {
                const bf16x8 ah0 = *(const bf16x8*)(a0h + k0);
                const bf16x8 al0 = *(const bf16x8*)(a0l + k0);
                const bf16x8 ah1 = *(const bf16x8*)(a1h + k0);
                const bf16x8 al1 = *(const bf16x8*)(a1l + k0);
                #pragma unroll
                for (int nt = 0; nt < 2; ++nt) {
                    const size_t n = wv * 32 + nt * 16 + l15;
                    const bf16x8 bh = *(const bf16x8*)(Wh + n * KK2 + k0 + quad * 8);
                    const bf16x8 bl = *(const bf16x8*)(Wl + n * KK2 + k0 + quad * 8);
                    acc[0][nt] = __builtin_amdgcn_mfma_f32_16x16x32_bf16(ah0, bh, acc[0][nt], 0, 0, 0);
                    acc[0][nt] = __builtin_amdgcn_mfma_f32_16x16x32_bf16(ah0, bl, acc[0][nt], 0, 0, 0);
                    acc[0][nt] = __builtin_amdgcn_mfma_f32_16x16x32_bf16(al0, bh, acc[0][nt], 0, 0, 0);
                    acc[1][nt] = __builtin_amdgcn_mfma_f32_16x16x32_bf16(ah1, bh, acc[1][nt], 0, 0, 0);
                    acc[1][nt] = __builtin_amdgcn_mfma_f32_16x16x32_bf16(ah1, bl, acc[1][nt], 0, 0, 0);
                    acc[1][nt] = __builtin_amdgcn_mfma_f32_16x16x32_bf16(al1, bh, acc[1][nt], 0, 0, 0);
                }
            }
            __syncthreads();   // all waves done READING hA from xs
            #pragma unroll
            for (int mt = 0; mt < 2; ++mt)
                #pragma unroll
                for (int nt = 0; nt < 2; ++nt) {
                    const int n = wv * 32 + nt * 16 + l15;
                    #pragma unroll
                    for (int r = 0; r < 4; ++r) {
                        const int m = mt * 16 + quad * 4 + r;
                        float v = fmaxf(acc[mt][nt][r], 0.f);
                        float rem;
                        xsh[m * XS_STRIDE + n] = f2bf_hi(v, &rem);
                        xsl[m * XS_STRIDE + n] = f2bf(rem);
                    }
                }
        }
        __syncthreads();

        // ---- layer 3: raw = h2 @ W3 + b3 (h2 read as hi+lo bf16 pair) ----
        if (br == 0) {
            const int q = t >> 4, c = t & 15;
            float s = ob3[c];
            const float4* w4 = (const float4*)(w3t + c * 256);
            const unsigned short* hrow = xsh + q * XS_STRIDE;
            const unsigned short* lrow = xsl + q * XS_STRIDE;
            for (int k = 0; k < 256; k += 8) {
                const u16x8 hi = *(const u16x8*)(hrow + k);
                const u16x8 lo = *(const u16x8*)(lrow + k);
                const float4 wa = w4[(k >> 2)];
                const float4 wb = w4[(k >> 2) + 1];
                s += (bf2f(hi[0]) + bf2f(lo[0])) * wa.x + (bf2f(hi[1]) + bf2f(lo[1])) * wa.y
                   + (bf2f(hi[2]) + bf2f(lo[2])) * wa.z + (bf2f(hi[3]) + bf2f(lo[3])) * wa.w
                   + (bf2f(hi[4]) + bf2f(lo[4])) * wb.x + (bf2f(hi[5]) + bf2f(lo[5])) * wb.y
                   + (bf2f(hi[6]) + bf2f(lo[6])) * wb.z + (bf2f(hi[7]) + bf2f(lo[7])) * wb.w;
            }
            raw[q * 24 + c] = s;
        } else if (t < TQ * 8) {
            const int q = t >> 3, c = t & 7;
            float s = wb3[c];
            const float4* w4 = (const float4*)(w3t + (16 + c) * 256);
            const unsigned short* hrow = xsh + q * XS_STRIDE;
            const unsigned short* lrow = xsl + q * XS_STRIDE;
            for (int k = 0; k < 256; k += 8) {
                const u16x8 hi = *(const u16x8*)(hrow + k);
                const u16x8 lo = *(const u16x8*)(lrow + k);
                const float4 wa = w4[(k >> 2)];
                const float4 wb = w4[(k >> 2) + 1];
                s += (bf2f(hi[0]) + bf2f(lo[0])) * wa.x + (bf2f(hi[1]) + bf2f(lo[1])) * wa.y
                   + (bf2f(hi[2]) + bf2f(lo[2])) * wa.z + (bf2f(hi[3]) + bf2f(lo[3])) * wa.w
                   + (bf2f(hi[4]) + bf2f(lo[4])) * wb.x + (bf2f(hi[5]) + bf2f(lo[5])) * wb.y
                   + (bf2f(hi[6]) + bf2f(lo[6])) * wb.z + (bf2f(hi[7]) + bf2f(lo[7])) * wb.w;
            }
            raw[q * 24 + 16 + c] = s;
        }
        __syncthreads();
    }

    // ---- epilogue: tanh, softmax -> compact sample records to global ----
    if (t < TQ) {
        const int q = t;
        float m = -1e30f;
        #pragma unroll
        for (int p = 0; p < 8; ++p) m = fmaxf(m, raw[q * 24 + 16 + p]);
        float e[8]; float S = 0.f;
        #pragma unroll
        for (int p = 0; p < 8; ++p) { e[p] = expf(raw[q * 24 + 16 + p] - m); S += e[p]; }
        float s2 = 0.f;
        #pragma unroll
        for (int p = 0; p < 8; ++p) { e[p] /= S; s2 += e[p]; }
        const float inv = 1.f / fmaxf(s2, 1e-8f);

        const float px = pcs[q * 2 + 0], py = pcs[q * 2 + 1];
        #pragma unroll
        for (int p = 0; p < 8; ++p) {
            const float cx = px + 2.f * tanhf(raw[q * 24 + 2 * p]);
            const float cy = py + 2.f * tanhf(raw[q * 24 + 2 * p + 1]);
            const float gx = fminf(fmaxf(2.f * cx * (1.f / (WW - 1)) - 1.f, -1.1f), 1.1f);
            const float gy = fminf(fmaxf(2.f * cy * (1.f / (HH - 1)) - 1.f, -1.1f), 1.1f);
            const float ix = fminf(fmaxf((gx + 1.f) * 0.5f * (WW - 1), 0.f), (float)(WW - 1));
            const float iy = fminf(fmaxf((gy + 1.f) * 0.5f * (HH - 1), 0.f), (float)(HH - 1));
            const float x0 = floorf(ix), y0 = floorf(iy);
            const float wx = ix - x0, wy = iy - y0;
            const int cell = (int)y0 * WW + (int)x0;
            float4 rec;
            rec.x = __int_as_float(cell);
            rec.y = wx; rec.z = wy; rec.w = e[p] * inv;
            sp[(size_t)(q0 + q) * 8 + p] = rec;
        }
    }
}

// ---------------------------------------------------------------------------
// gather: high-occupancy (tiny LDS, VGPR<=64) bilinear gather + weighted sum
// ---------------------------------------------------------------------------
__launch_bounds__(256, 8)
__global__ void gather_kernel(const float* __restrict__ fmap,
                              const float4* __restrict__ sp,
                              float* __restrict__ out) {
    __shared__ float4 spb[GQB * 8];
    const int t    = threadIdx.x;
    const int q0   = blockIdx.x * GQB;
    const int lane = t & 63;
    const int wv   = t >> 6;

    if (t < GQB * 8) spb[t] = sp[(size_t)q0 * 8 + t];
    __syncthreads();

    const float4* fm4 = (const float4*)fmap;
    float4 acc; acc.x = acc.y = acc.z = acc.w = 0.f;
    for (int p = 0; p < 8; ++p) {
        const float4 d = spb[wv * 8 + p];           // uniform addr -> broadcast
        const int cell = __float_as_int(d.x);
        const int x0 = cell & (WW - 1), y0 = cell >> 9;
        const int x1 = min(x0 + 1, WW - 1), y1 = min(y0 + 1, HH - 1);
        const float wx = d.y, wy = d.z, nwp = d.w;
        const float w00 = (1.f - wx) * (1.f - wy) * nwp;
        const float w01 = wx * (1.f - wy) * nwp;
        const float w10 = (1.f - wx) * wy * nwp;
        const float w11 = wx * wy * nwp;
        const int b00 = (y0 * WW + x0) * (CC / 4) + lane;
        const int b01 = (y0 * WW + x1) * (CC / 4) + lane;
        const int b10 = (y1 * WW + x0) * (CC / 4) + lane;
        const int b11 = (y1 * WW + x1) * (CC / 4) + lane;
        const float4 v00 = fm4[b00], v01 = fm4[b01], v10 = fm4[b10], v11 = fm4[b11];
        acc.x += w00 * v00.x + w01 * v01.x + w10 * v10.x + w11 * v11.x;
        acc.y += w00 * v00.y + w01 * v01.y + w10 * v10.y + w11 * v11.y;
        acc.z += w00 * v00.z + w01 * v01.z + w10 * v10.z + w11 * v11.z;
        acc.w += w00 * v00.w + w01 * v01.w + w10 * v10.w + w11 * v11.w;
    }
    ((float4*)out)[(size_t)(q0 + wv) * (CC / 4) + lane] = acc;
}

extern "C" void kernel_launch(void* const* d_in, const int* in_sizes, int n_in,
                              void* d_out, int out_size, void* d_ws, size_t ws_size,
                              hipStream_t stream) {
    const float* gq   = (const float*)d_in[0];
    const float* pc   = (const float*)d_in[1];
    const float* fmap = (const float*)d_in[2];
    const float* og   = (const float*)d_in[3];
    const float* obl  = (const float*)d_in[4];
    const float* oW1  = (const float*)d_in[5];
    const float* ob1  = (const float*)d_in[6];
    const float* oW2  = (const float*)d_in[7];
    const float* ob2  = (const float*)d_in[8];
    const float* oW3  = (const float*)d_in[9];
    const float* ob3  = (const float*)d_in[10];
    const float* wg   = (const float*)d_in[11];
    const float* wbl  = (const float*)d_in[12];
    const float* wW1  = (const float*)d_in[13];
    const float* wb1  = (const float*)d_in[14];
    const float* wW2  = (const float*)d_in[15];
    const float* wb2  = (const float*)d_in[16];
    const float* wW3  = (const float*)d_in[17];
    const float* wb3  = (const float*)d_in[18];

    char* ws = (char*)d_ws;
    unsigned short* w1th = (unsigned short*)(ws + WS_W1TH);
    unsigned short* w1tl = (unsigned short*)(ws + WS_W1TL);
    unsigned short* w2th = (unsigned short*)(ws + WS_W2TH);
    unsigned short* w2tl = (unsigned short*)(ws + WS_W2TL);
    float* w3t = (float*)(ws + WS_W3T);
    float* b1e = (float*)(ws + WS_B1E);
    float4* sp = (float4*)(ws + WS_SP);
    float* out = (float*)d_out;

    prep_w1<<<dim3(KK1, 2), 256, 0, stream>>>(og, obl, oW1, ob1, wg, wbl, wW1, wb1, w1th, w1tl, b1e);
    prep_w2<<<dim3(KK2, 2), 256, 0, stream>>>(oW2, wW2, w2th, w2tl);
    prep_w3<<<2, 256, 0, stream>>>(oW3, wW3, w3t);
    mlp_kernel<<<NQ / TQ, NTHR, 0, stream>>>(gq, pc, w1th, w1tl, w2th, w2tl, w3t, b1e,
                                             ob2, ob3, wb2, wb3, sp);
    gather_kernel<<<NQ / GQB, 256, 0, stream>>>(fmap, sp, out);
}